// Round 6
// baseline (95.106 us; speedup 1.0000x reference)
//
#include <hip/hip_runtime.h>
#include <math.h>

// Problem constants
#define NPIX    65536      // 256*256 pixels per camera
#define NBINS   64
#define NBATCH  32         // B*C = 4*8
#define SPLIT   32         // pixel-chunks per batch
#define BLOCKT  128        // 2 waves/block
#define PXPT    4          // pixels per thread per iteration
#define ITERS   (NPIX / SPLIT / (BLOCKT * PXPT))   // = 4 -> 16 px/thread
#define HSTRIDE 68         // dwords/thread: 16B-aligned base
#define LDSN    (BLOCKT * HSTRIDE)                 // 8704 floats = 34.8 KB -> 4 blocks/CU
#define WIN     12         // 4-aligned window, guaranteed coverage [j0-4, j0+4] both sides
                           // (R4-measured absmax 2.3e-10; R5's WIN=8 left only 4% margin)

#define THREE_LOG2E 4.328085122666891f

struct Pix { float4 n0, n1, n2, i0, i1, i2, f0, f1, f2, c; };

__global__ __launch_bounds__(BLOCKT, 2) void spad_hist_kernel(
    const float* __restrict__ normals,      // [32, 65536, 3]
    const float* __restrict__ inters,       // [32, 65536, 3]
    const float* __restrict__ film,         // [65536, 3]
    const float* __restrict__ cosm,         // [65536]
    float* __restrict__ ws,                 // [1024, 64] block partials
    float kconst, float lmask_c, float half_inv_bin)
{
    // Thread-private LDS histograms, no atomics. 16B-aligned windows -> b128 RMW.
    __shared__ float hist[LDSN];
    const int tid = threadIdx.x;
    {   // zero own region with b128 stores
        float4* h4 = (float4*)&hist[tid * HSTRIDE];
        #pragma unroll
        for (int i = 0; i < HSTRIDE / 4; ++i) h4[i] = make_float4(0.f, 0.f, 0.f, 0.f);
    }
    __syncthreads();

    const int b = blockIdx.x & (NBATCH - 1);
    const int chunk = blockIdx.x / NBATCH;
    const int pix0 = chunk * (NPIX / SPLIT);
    const int base = tid * HSTRIDE;

    // E3^m, m=0..12 — independent scaling breaks the serial exp chain
    const float E3P[13] = {
        1.0f, 20.085536923187668f, 403.4287934927351f, 8103.083927575384f,
        162754.79141900392f, 3269017.372472111f, 65659969.13733051f,
        1318815734.4832146f, 26489122129.843472f, 532048240601.79865f,
        10686474581524.462f, 214643579785916.06f, 4311231547115195.0f };

    auto loadPix = [&](int it) {
        Pix P;
        const int pp = pix0 + (it * BLOCKT + tid) * PXPT;
        const float4* n4 = (const float4*)(normals + ((size_t)b * NPIX + pp) * 3);
        const float4* i4 = (const float4*)(inters  + ((size_t)b * NPIX + pp) * 3);
        const float4* f4 = (const float4*)(film + (size_t)pp * 3);
        P.n0 = n4[0]; P.n1 = n4[1]; P.n2 = n4[2];
        P.i0 = i4[0]; P.i1 = i4[1]; P.i2 = i4[2];
        P.f0 = f4[0]; P.f1 = f4[1]; P.f2 = f4[2];
        P.c  = *(const float4*)(cosm + pp);
        return P;
    };

    // 2-deep software pipeline: iteration it+1's loads are in flight while
    // iteration it computes (covers HBM latency with only 8 waves/CU)
    Pix cur = loadPix(0);

    #pragma unroll
    for (int it = 0; it < ITERS; ++it) {
        Pix nxt = cur;
        if (it + 1 < ITERS) nxt = loadPix(it + 1);

        // gather 4 pixels into arrays (SoA in registers)
        float NX[4] = {cur.n0.x, cur.n0.w, cur.n1.z, cur.n2.y},
              NY[4] = {cur.n0.y, cur.n1.x, cur.n1.w, cur.n2.z},
              NZ[4] = {cur.n0.z, cur.n1.y, cur.n2.x, cur.n2.w};
        float IX[4] = {cur.i0.x, cur.i0.w, cur.i1.z, cur.i2.y},
              IY[4] = {cur.i0.y, cur.i1.x, cur.i1.w, cur.i2.z},
              IZ[4] = {cur.i0.z, cur.i1.y, cur.i2.x, cur.i2.w};
        float FX[4] = {cur.f0.x, cur.f0.w, cur.f1.z, cur.f2.y},
              FY[4] = {cur.f0.y, cur.f1.x, cur.f1.w, cur.f2.z},
              FZ[4] = {cur.f0.z, cur.f1.y, cur.f2.x, cur.f2.w};
        float CM[4] = {cur.c.x, cur.c.y, cur.c.z, cur.c.w};

        int   K0[4];
        float W[4][WIN];   // final per-bin weights r*(s_m - s_{m+1})

        // Phase 1: all geometry + sigmoids + weights (4 independent chains -> ILP)
        #pragma unroll
        for (int p = 0; p < 4; ++p) {
            float dt = FX[p] * NX[p] + FY[p] * NY[p] + FZ[p] * NZ[p];
            dt = fminf(fmaxf(dt, 0.0f), 1.0f);
            float lx = IX[p] - 0.002f;
            float lxy2 = lx * lx + IY[p] * IY[p];
            float l2 = lxy2 + IZ[p] * IZ[p];
            float ld = __builtin_amdgcn_sqrtf(l2);
            float lm = __builtin_amdgcn_exp2f(
                lmask_c * lxy2 * __builtin_amdgcn_rcpf(IZ[p] * IZ[p]));
            float cm3 = CM[p] * CM[p] * CM[p];
            float r = dt * lm * kconst * cm3 * __builtin_amdgcn_rcpf(l2);
            float di = __builtin_amdgcn_sqrtf(
                IX[p] * IX[p] + IY[p] * IY[p] + IZ[p] * IZ[p]);
            float d = (di + ld) * half_inv_bin;     // depth in bin units

            int j0 = (int)floorf(d);
            j0 = j0 < 4 ? 4 : (j0 > 56 ? 56 : j0);
            int k0 = (j0 - 4) & ~3;                 // 4-aligned, in [0, 52]
            K0[p] = k0;
            float e0 = __builtin_amdgcn_exp2f(((float)k0 - d) * THREE_LOG2E);
            float S[WIN + 1];
            #pragma unroll
            for (int m = 0; m < WIN + 1; ++m)       // independent fma+rcp
                S[m] = __builtin_amdgcn_rcpf(fmaf(e0, E3P[m], 1.0f));
            #pragma unroll
            for (int m = 0; m < WIN; ++m)
                W[p][m] = r * (S[m] - S[m + 1]);
        }

        // Phase 2: per-pixel b128 RMW (ordered; same-thread windows may alias,
        // DS pipe is in-order per wave so read-after-write is safe)
        #pragma unroll
        for (int p = 0; p < 4; ++p) {
            float4* hp = (float4*)&hist[base + K0[p]];
            float4 a = hp[0], bb = hp[1], c = hp[2];
            a.x  += W[p][0];  a.y  += W[p][1];  a.z  += W[p][2];  a.w  += W[p][3];
            bb.x += W[p][4];  bb.y += W[p][5];  bb.z += W[p][6];  bb.w += W[p][7];
            c.x  += W[p][8];  c.y  += W[p][9];  c.z  += W[p][10]; c.w  += W[p][11];
            hp[0] = a; hp[1] = bb; hp[2] = c;
        }

        cur = nxt;
    }
    __syncthreads();

    // 3-phase float4 reduction of 128 private histograms
    const int g = tid & 15;      // bin group: bins 4g..4g+3
    const int h = tid >> 4;      // hist subset start
    float4 acc = make_float4(0.f, 0.f, 0.f, 0.f);
    #pragma unroll
    for (int j = 0; j < 16; ++j) {
        float4 v = *(const float4*)&hist[(h + 8 * j) * HSTRIDE + 4 * g];
        acc.x += v.x; acc.y += v.y; acc.z += v.z; acc.w += v.w;
    }
    __syncthreads();
    *(float4*)&hist[tid * 4] = acc;   // partial[h][g] at dword h*64 + 4g
    __syncthreads();
    if (tid < 16) {
        float4 s4 = make_float4(0.f, 0.f, 0.f, 0.f);
        #pragma unroll
        for (int hh = 0; hh < 8; ++hh) {
            float4 v = *(const float4*)&hist[hh * 64 + tid * 4];
            s4.x += v.x; s4.y += v.y; s4.z += v.z; s4.w += v.w;
        }
        *(float4*)&ws[(size_t)blockIdx.x * NBINS + tid * 4] = s4;
    }
}

__global__ __launch_bounds__(256) void spad_reduce_kernel(
    const float* __restrict__ ws, float* __restrict__ out)
{
    const int o = blockIdx.x * 256 + threadIdx.x;  // 0..2047 -> (b, k)
    const int b = o >> 6;
    const int k = o & 63;
    float s = 0.0f;
    #pragma unroll
    for (int c = 0; c < SPLIT; ++c)
        s += ws[((size_t)(c * NBATCH + b)) * NBINS + k];
    out[o] = s;   // every element written -> no memset needed
}

extern "C" void kernel_launch(void* const* d_in, const int* in_sizes, int n_in,
                              void* d_out, int out_size, void* d_ws, size_t ws_size,
                              hipStream_t stream) {
    const float* normals = (const float*)d_in[0];
    const float* inters  = (const float*)d_in[1];
    const float* film    = (const float*)d_in[2];
    const float* cosm    = (const float*)d_in[3];
    float* out = (float*)d_out;
    float* ws  = (float*)d_ws;   // needs 1024*64*4 = 256 KiB

    // host-side double-precision constants (argument setup; capture-safe)
    const double fov_rad = 33.0 * M_PI / 180.0;
    const double width = 2.0 * tan(fov_rad / 2.0);
    const double kconst_d = width * width / M_PI / 65536.0;       // width^2/pi/R^2
    const double sig = tan(21.5 * M_PI / 180.0) / 1.4;
    const double log2e = 1.4426950408889634;
    const double lmask_c_d = -log2e / (2.0 * sig * sig);          // exp2 scale
    const double half_inv_bin_d = 0.5 / 0.0136;

    spad_hist_kernel<<<NBATCH * SPLIT, BLOCKT, 0, stream>>>(
        normals, inters, film, cosm, ws,
        (float)kconst_d, (float)lmask_c_d, (float)half_inv_bin_d);

    spad_reduce_kernel<<<(NBATCH * NBINS) / 256, 256, 0, stream>>>(ws, out);
}

// Round 7
// 92.637 us; speedup vs baseline: 1.0267x; 1.0267x over previous
//
#include <hip/hip_runtime.h>
#include <math.h>

// Problem constants
#define NPIX    65536      // 256*256 pixels per camera
#define NBINS   64
#define NBATCH  32         // B*C = 4*8
#define SPLIT   32         // pixel-chunks per batch
#define BLOCKT  128        // 2 waves/block
#define PXPT    4          // pixels per thread per iteration
#define ITERS   (NPIX / SPLIT / (BLOCKT * PXPT))   // = 4 -> 16 px/thread
#define HSTRIDE 68         // dwords/thread: 16B-aligned base
#define LDSN    (BLOCKT * HSTRIDE)                 // 8704 floats = 34.8 KB -> 4 blocks/CU
#define WIN     12         // 4-aligned window, guaranteed coverage [j0-4, j0+4] both sides
                           // (R4/R6-measured absmax 2.3e-10; WIN=8 left only 4% margin — R5)
// NOTE (R6): 2-deep software prefetch of the global loads REGRESSED 92.8->95.1 us
// (double-buffer register copies outweigh latency hiding at 2 waves/SIMD). Keep
// the simple per-iteration load; the kernel is issue-bound, not VMEM-latency-bound.

#define THREE_LOG2E 4.328085122666891f

__global__ __launch_bounds__(BLOCKT, 2) void spad_hist_kernel(
    const float* __restrict__ normals,      // [32, 65536, 3]
    const float* __restrict__ inters,       // [32, 65536, 3]
    const float* __restrict__ film,         // [65536, 3]
    const float* __restrict__ cosm,         // [65536]
    float* __restrict__ ws,                 // [1024, 64] block partials
    float kconst, float lmask_c, float half_inv_bin)
{
    // Thread-private LDS histograms, no atomics. 16B-aligned windows -> b128 RMW.
    __shared__ float hist[LDSN];
    const int tid = threadIdx.x;
    {   // zero own region with b128 stores
        float4* h4 = (float4*)&hist[tid * HSTRIDE];
        #pragma unroll
        for (int i = 0; i < HSTRIDE / 4; ++i) h4[i] = make_float4(0.f, 0.f, 0.f, 0.f);
    }
    __syncthreads();

    const int b = blockIdx.x & (NBATCH - 1);
    const int chunk = blockIdx.x / NBATCH;
    const int pix0 = chunk * (NPIX / SPLIT);
    const int base = tid * HSTRIDE;

    // E3^m, m=0..12 — independent scaling breaks the serial exp chain
    const float E3P[13] = {
        1.0f, 20.085536923187668f, 403.4287934927351f, 8103.083927575384f,
        162754.79141900392f, 3269017.372472111f, 65659969.13733051f,
        1318815734.4832146f, 26489122129.843472f, 532048240601.79865f,
        10686474581524.462f, 214643579785916.06f, 4311231547115195.0f };

    #pragma unroll
    for (int it = 0; it < ITERS; ++it) {
        const int pp = pix0 + (it * BLOCKT + tid) * PXPT;
        const float4* n4 = (const float4*)(normals + ((size_t)b * NPIX + pp) * 3);
        const float4* i4 = (const float4*)(inters  + ((size_t)b * NPIX + pp) * 3);
        const float4* f4 = (const float4*)(film + (size_t)pp * 3);
        const float4  c4 = *(const float4*)(cosm + pp);
        float4 n0 = n4[0], n1 = n4[1], n2 = n4[2];
        float4 i0 = i4[0], i1 = i4[1], i2 = i4[2];
        float4 f0 = f4[0], f1 = f4[1], f2 = f4[2];

        // gather 4 pixels into arrays (SoA in registers)
        float NX[4] = {n0.x, n0.w, n1.z, n2.y}, NY[4] = {n0.y, n1.x, n1.w, n2.z},
              NZ[4] = {n0.z, n1.y, n2.x, n2.w};
        float IX[4] = {i0.x, i0.w, i1.z, i2.y}, IY[4] = {i0.y, i1.x, i1.w, i2.z},
              IZ[4] = {i0.z, i1.y, i2.x, i2.w};
        float FX[4] = {f0.x, f0.w, f1.z, f2.y}, FY[4] = {f0.y, f1.x, f1.w, f2.z},
              FZ[4] = {f0.z, f1.y, f2.x, f2.w};
        float CM[4] = {c4.x, c4.y, c4.z, c4.w};

        int   K0[4];
        float W[4][WIN];   // final per-bin weights r*(s_m - s_{m+1})

        // Phase 1: all geometry + sigmoids + weights (4 independent chains -> ILP)
        #pragma unroll
        for (int p = 0; p < 4; ++p) {
            float dt = FX[p] * NX[p] + FY[p] * NY[p] + FZ[p] * NZ[p];
            dt = fminf(fmaxf(dt, 0.0f), 1.0f);
            float lx = IX[p] - 0.002f;
            float lxy2 = lx * lx + IY[p] * IY[p];
            float l2 = lxy2 + IZ[p] * IZ[p];
            float ld = __builtin_amdgcn_sqrtf(l2);
            float lm = __builtin_amdgcn_exp2f(
                lmask_c * lxy2 * __builtin_amdgcn_rcpf(IZ[p] * IZ[p]));
            float cm3 = CM[p] * CM[p] * CM[p];
            float r = dt * lm * kconst * cm3 * __builtin_amdgcn_rcpf(l2);
            float di = __builtin_amdgcn_sqrtf(
                IX[p] * IX[p] + IY[p] * IY[p] + IZ[p] * IZ[p]);
            float d = (di + ld) * half_inv_bin;     // depth in bin units

            int j0 = (int)floorf(d);
            j0 = j0 < 4 ? 4 : (j0 > 56 ? 56 : j0);
            int k0 = (j0 - 4) & ~3;                 // 4-aligned, in [0, 52]
            K0[p] = k0;
            float e0 = __builtin_amdgcn_exp2f(((float)k0 - d) * THREE_LOG2E);
            float S[WIN + 1];
            #pragma unroll
            for (int m = 0; m < WIN + 1; ++m)       // independent fma+rcp
                S[m] = __builtin_amdgcn_rcpf(fmaf(e0, E3P[m], 1.0f));
            #pragma unroll
            for (int m = 0; m < WIN; ++m)
                W[p][m] = r * (S[m] - S[m + 1]);
        }

        // Phase 2: per-pixel b128 RMW (ordered; same-thread windows may alias,
        // DS pipe is in-order per wave so read-after-write is safe)
        #pragma unroll
        for (int p = 0; p < 4; ++p) {
            float4* hp = (float4*)&hist[base + K0[p]];
            float4 a = hp[0], bb = hp[1], c = hp[2];
            a.x  += W[p][0];  a.y  += W[p][1];  a.z  += W[p][2];  a.w  += W[p][3];
            bb.x += W[p][4];  bb.y += W[p][5];  bb.z += W[p][6];  bb.w += W[p][7];
            c.x  += W[p][8];  c.y  += W[p][9];  c.z  += W[p][10]; c.w  += W[p][11];
            hp[0] = a; hp[1] = bb; hp[2] = c;
        }
    }
    __syncthreads();

    // 3-phase float4 reduction of 128 private histograms
    const int g = tid & 15;      // bin group: bins 4g..4g+3
    const int h = tid >> 4;      // hist subset start
    float4 acc = make_float4(0.f, 0.f, 0.f, 0.f);
    #pragma unroll
    for (int j = 0; j < 16; ++j) {
        float4 v = *(const float4*)&hist[(h + 8 * j) * HSTRIDE + 4 * g];
        acc.x += v.x; acc.y += v.y; acc.z += v.z; acc.w += v.w;
    }
    __syncthreads();
    *(float4*)&hist[tid * 4] = acc;   // partial[h][g] at dword h*64 + 4g
    __syncthreads();
    if (tid < 16) {
        float4 s4 = make_float4(0.f, 0.f, 0.f, 0.f);
        #pragma unroll
        for (int hh = 0; hh < 8; ++hh) {
            float4 v = *(const float4*)&hist[hh * 64 + tid * 4];
            s4.x += v.x; s4.y += v.y; s4.z += v.z; s4.w += v.w;
        }
        *(float4*)&ws[(size_t)blockIdx.x * NBINS + tid * 4] = s4;
    }
}

__global__ __launch_bounds__(256) void spad_reduce_kernel(
    const float* __restrict__ ws, float* __restrict__ out)
{
    const int o = blockIdx.x * 256 + threadIdx.x;  // 0..2047 -> (b, k)
    const int b = o >> 6;
    const int k = o & 63;
    float s = 0.0f;
    #pragma unroll
    for (int c = 0; c < SPLIT; ++c)
        s += ws[((size_t)(c * NBATCH + b)) * NBINS + k];
    out[o] = s;   // every element written -> no memset needed
}

extern "C" void kernel_launch(void* const* d_in, const int* in_sizes, int n_in,
                              void* d_out, int out_size, void* d_ws, size_t ws_size,
                              hipStream_t stream) {
    const float* normals = (const float*)d_in[0];
    const float* inters  = (const float*)d_in[1];
    const float* film    = (const float*)d_in[2];
    const float* cosm    = (const float*)d_in[3];
    float* out = (float*)d_out;
    float* ws  = (float*)d_ws;   // needs 1024*64*4 = 256 KiB

    // host-side double-precision constants (argument setup; capture-safe)
    const double fov_rad = 33.0 * M_PI / 180.0;
    const double width = 2.0 * tan(fov_rad / 2.0);
    const double kconst_d = width * width / M_PI / 65536.0;       // width^2/pi/R^2
    const double sig = tan(21.5 * M_PI / 180.0) / 1.4;
    const double log2e = 1.4426950408889634;
    const double lmask_c_d = -log2e / (2.0 * sig * sig);          // exp2 scale
    const double half_inv_bin_d = 0.5 / 0.0136;

    spad_hist_kernel<<<NBATCH * SPLIT, BLOCKT, 0, stream>>>(
        normals, inters, film, cosm, ws,
        (float)kconst_d, (float)lmask_c_d, (float)half_inv_bin_d);

    spad_reduce_kernel<<<(NBATCH * NBINS) / 256, 256, 0, stream>>>(ws, out);
}